// Round 4
// baseline (279.311 us; speedup 1.0000x reference)
//
#include <hip/hip_runtime.h>
#include <hip/hip_bf16.h>
#include <math.h>

#define B_SZ   16
#define N_ATOM 286
#define NT     1024            // table entries, r_e = 3*e/(NT-1)
#define HIDW   150
#define FF_DIM 512
#define TILE   38              // output-neuron tile per wave (4 waves cover 150)
#define ROWS_BLK 16            // conv rows per block

__device__ __forceinline__ float softplus_f(float x) {
  return fmaxf(x, 0.0f) + log1pf(expf(-fabsf(x)));
}
// torch Softplus(beta=5): softplus(5x)/5
__device__ __forceinline__ float sp5_f(float x) {
  float t = 5.0f * x;
  return (fmaxf(t, 0.0f) + log1pf(expf(-fabsf(t)))) * 0.2f;
}

// Tabulate radial MLP R(r) at NT points, both clouds in one launch.
// Block = 256 thr = 4 waves; lane = entry (64 entries per block).
// Wave w owns output-neuron tile [o0, o0+38); weights are wave-uniform
// (readfirstlane -> s_load); activations exchanged via LDS [i][entry]
// (stride-1 coalesced ds_read_b32, conflict-free).
__global__ __launch_bounds__(256) void table_kernel(
    const float* __restrict__ a_w0, const float* __restrict__ a_b0,
    const float* __restrict__ a_w1, const float* __restrict__ a_b1,
    const float* __restrict__ a_w2, const float* __restrict__ a_b2,
    const float* __restrict__ a_w3, const float* __restrict__ a_b3,
    const float* __restrict__ c_w0, const float* __restrict__ c_b0,
    const float* __restrict__ c_w1, const float* __restrict__ c_b1,
    const float* __restrict__ c_w2, const float* __restrict__ c_b2,
    const float* __restrict__ c_w3, const float* __restrict__ c_b3,
    float* __restrict__ tab0, float* __restrict__ tab1) {
  __shared__ float hb0[HIDW * 64];   // 38.4 KB
  __shared__ float hb1[HIDW * 64];   // 38.4 KB  (also reused for layer-3 partials)

  const int nblk = NT / 64;
  const int cloud = (blockIdx.x >= nblk) ? 1 : 0;
  const int blk   = blockIdx.x - cloud * nblk;
  const float* w0 = cloud ? c_w0 : a_w0;  const float* b0 = cloud ? c_b0 : a_b0;
  const float* w1 = cloud ? c_w1 : a_w1;  const float* b1 = cloud ? c_b1 : a_b1;
  const float* w2 = cloud ? c_w2 : a_w2;  const float* b2 = cloud ? c_b2 : a_b2;
  const float* w3 = cloud ? c_w3 : a_w3;  const float* b3 = cloud ? c_b3 : a_b3;
  float* table = cloud ? tab1 : tab0;

  const int tid  = threadIdx.x;
  const int e    = tid & 63;                  // entry within block (lane)
  int wave = tid >> 6;
  wave = __builtin_amdgcn_readfirstlane(wave);              // force SGPR
  const int o0 = __builtin_amdgcn_readfirstlane((wave < 3) ? wave * TILE : HIDW - TILE); // 0,38,76,112

  const int entry = blk * 64 + e;
  const float r = 3.0f * (float)entry / (float)(NT - 1);

  // cosine basis (3 values), per lane
  float x0, x1, x2;
  {
    float xv[3];
    #pragma unroll
    for (int k = 0; k < 3; ++k) {
      float d = (r - 1.5f * (float)k) * (1.0f / 1.5f);
      float c = cosf(1.57079632679489662f * d);
      xv[k] = (fabsf(d) < 1.0f) ? c * c : 0.0f;
    }
    x0 = xv[0]; x1 = xv[1]; x2 = xv[2];
  }

  // ---- layer 0: 3 -> 150 (tiles may overlap at o=112..113: benign dup) ----
  #pragma unroll
  for (int j = 0; j < TILE; ++j) {
    int o = o0 + j;
    float h = sp5_f(b0[o] + x0 * w0[o] + x1 * w0[HIDW + o] + x2 * w0[2 * HIDW + o]);
    hb0[o * 64 + e] = h;
  }
  __syncthreads();

  // ---- layers 1,2: 150 -> 150 ----
  {
    // layer 1: read hb0, write hb1
    float acc[TILE];
    #pragma unroll
    for (int j = 0; j < TILE; ++j) acc[j] = b1[o0 + j];
    for (int i = 0; i < HIDW; ++i) {
      float hv = hb0[i * 64 + e];
      const float* __restrict__ Wr = w1 + i * HIDW + o0;
      #pragma unroll
      for (int j = 0; j < TILE; ++j) acc[j] = __builtin_fmaf(hv, Wr[j], acc[j]);
    }
    __syncthreads();   // all layer-1 reads of hb0 done
    #pragma unroll
    for (int j = 0; j < TILE; ++j) hb1[(o0 + j) * 64 + e] = sp5_f(acc[j]);
    __syncthreads();
  }
  {
    // layer 2: read hb1, write hb0
    float acc[TILE];
    #pragma unroll
    for (int j = 0; j < TILE; ++j) acc[j] = b2[o0 + j];
    for (int i = 0; i < HIDW; ++i) {
      float hv = hb1[i * 64 + e];
      const float* __restrict__ Wr = w2 + i * HIDW + o0;
      #pragma unroll
      for (int j = 0; j < TILE; ++j) acc[j] = __builtin_fmaf(hv, Wr[j], acc[j]);
    }
    __syncthreads();
    #pragma unroll
    for (int j = 0; j < TILE; ++j) hb0[(o0 + j) * 64 + e] = sp5_f(acc[j]);
    __syncthreads();
  }

  // ---- layer 3: 150 -> 16, i-range split across waves, partials in hb1 ----
  {
    const int i0 = __builtin_amdgcn_readfirstlane(
        (wave == 0) ? 0 : (wave == 1) ? 38 : (wave == 2) ? 76 : 112);
    const int i1 = __builtin_amdgcn_readfirstlane(
        (wave == 0) ? 38 : (wave == 1) ? 76 : (wave == 2) ? 112 : 150);
    float p[16];
    #pragma unroll
    for (int q = 0; q < 16; ++q) p[q] = 0.0f;
    for (int i = i0; i < i1; ++i) {
      float hv = hb0[i * 64 + e];
      const float* __restrict__ Wr = w3 + i * 16;
      #pragma unroll
      for (int q = 0; q < 16; ++q) p[q] = __builtin_fmaf(hv, Wr[q], p[q]);
    }
    #pragma unroll
    for (int q = 0; q < 16; ++q) hb1[(wave * 16 + q) * 64 + e] = p[q];
    __syncthreads();
    // final sum: wave w handles outputs o = w*4 .. w*4+3
    #pragma unroll
    for (int q = 0; q < 4; ++q) {
      int o = wave * 4 + q;
      float v = b3[o] + hb1[o * 64 + e] + hb1[(16 + o) * 64 + e]
                      + hb1[(32 + o) * 64 + e] + hb1[(48 + o) * 64 + e];
      table[(size_t)entry * 16 + o] = v;
    }
  }
}

// Conv: block stages the full table (64 KB, XOR-swizzled at float4 granularity)
// into LDS, then processes ROWS_BLK=16 output rows (4 per wave).
// conv1 fuses the emb[Z] gather (gather=1); conv2 reads feats_in (gather=0).
__global__ __launch_bounds__(256) void conv_kernel(
    const float* __restrict__ xyz, const int* __restrict__ Z,
    const float* __restrict__ emb, const float* __restrict__ feats_in,
    const float* __restrict__ table, float* __restrict__ f_out, int gather) {
  __shared__ float4 tab[NT * 4];   // 64 KB
  const int tid  = threadIdx.x;
  const int wave = tid >> 6;
  const int lane = tid & 63;

  // stage with swizzle: slot(idx,i) = idx*4 + (i ^ ((idx>>1)&3))
  {
    const float4* src = (const float4*)table;
    for (int k = tid; k < NT * 4; k += 256) {
      int gi = k >> 2, q = k & 3;
      tab[(k & ~3) | (q ^ ((gi >> 1) & 3))] = src[k];
    }
  }
  __syncthreads();

  #pragma unroll
  for (int rr = 0; rr < 4; ++rr) {
    const int row = blockIdx.x * ROWS_BLK + wave * 4 + rr;
    const int z = row / N_ATOM, a = row % N_ATOM;
    const float* xz = xyz + (size_t)z * N_ATOM * 3;
    const float ax = xz[a * 3 + 0], ay = xz[a * 3 + 1], az = xz[a * 3 + 2];

    float acc[4] = {0.f, 0.f, 0.f, 0.f};
    float cnt = 0.f;
    for (int b = lane; b < N_ATOM; b += 64) {
      float bx = xz[b * 3 + 0], by = xz[b * 3 + 1], bz = xz[b * 3 + 2];
      float dx = ax - bx, dy = ay - by, dz = az - bz;
      float r = sqrtf(dx * dx + dy * dy + dz * dz + 1e-12f);
      if (r < 3.0f) {
        cnt += 1.0f;
        float t = r * ((float)(NT - 1) / 3.0f);
        int idx = (int)t;
        if (idx > NT - 2) idx = NT - 2;
        float fr = t - (float)idx;
        int base0 = idx * 4,      sw0 = (idx >> 1) & 3;
        int base1 = base0 + 4,    sw1 = ((idx + 1) >> 1) & 3;
        float4 fb;
        if (gather) {
          int zi = Z[z * N_ATOM + b];
          fb = *(const float4*)(emb + (size_t)zi * 4);
        } else {
          fb = *(const float4*)(feats_in + ((size_t)z * N_ATOM + b) * 4);
        }
        #pragma unroll
        for (int i = 0; i < 4; ++i) {
          float4 r0 = tab[base0 + (i ^ sw0)];
          float4 r1 = tab[base1 + (i ^ sw1)];
          float v0 = r0.x + fr * (r1.x - r0.x);
          float v1 = r0.y + fr * (r1.y - r0.y);
          float v2 = r0.z + fr * (r1.z - r0.z);
          float v3 = r0.w + fr * (r1.w - r0.w);
          acc[i] += v0 * fb.x + v1 * fb.y + v2 * fb.z + v3 * fb.w;
        }
      }
    }
    #pragma unroll
    for (int m = 32; m > 0; m >>= 1) {
      #pragma unroll
      for (int i = 0; i < 4; ++i) acc[i] += __shfl_xor(acc[i], m, 64);
      cnt += __shfl_xor(cnt, m, 64);
    }
    if (lane == 0) {
      float nb = cnt < 1.0f ? 1.0f : cnt;
      float sc = 1.0f / sqrtf(nb);
      float4 o;
      o.x = acc[0] * sc; o.y = acc[1] * sc; o.z = acc[2] * sc; o.w = acc[3] * sc;
      *(float4*)(f_out + (size_t)row * 4) = o;
    }
  }
}

// L2 pool over atoms -> FC(8->512)+softplus -> batchnorm over B -> softplus
// -> FC(512->1) -> sigmoid.   Single block of 512 threads.
__global__ __launch_bounds__(512) void tail_kernel(
    const float* __restrict__ f1, const float* __restrict__ f2,
    const float* __restrict__ fc_w, const float* __restrict__ fc_b,
    const float* __restrict__ bn_g, const float* __restrict__ bn_b,
    const float* __restrict__ out_w, const float* __restrict__ out_b,
    float* __restrict__ out) {
  __shared__ float pooled[16][8];
  __shared__ float part[8][16];
  const int tid = threadIdx.x;

  // pooling: 4 threads per (z,c) column, 4-lane shuffle reduce
  {
    int pair = tid >> 2;            // 0..127
    int sub  = tid & 3;
    int z = pair >> 3, c = pair & 7;
    const float* src = (c < 4) ? f1 : f2;
    int cc = c & 3;
    float s = 0.f;
    for (int a = sub; a < N_ATOM; a += 4) {
      float v = src[((size_t)z * N_ATOM + a) * 4 + cc];
      s += v * v;
    }
    s += __shfl_xor(s, 1, 64);
    s += __shfl_xor(s, 2, 64);
    if (sub == 0) pooled[z][c] = sqrtf(s);
  }
  __syncthreads();

  const int f = tid;
  float hv[16];
  float mean = 0.f;
  #pragma unroll
  for (int z = 0; z < 16; ++z) {
    float a = fc_b[f];
    #pragma unroll
    for (int c = 0; c < 8; ++c) a += pooled[z][c] * fc_w[c * FF_DIM + f];
    hv[z] = softplus_f(a);
    mean += hv[z];
  }
  mean *= (1.0f / 16.0f);
  float var = 0.f;
  #pragma unroll
  for (int z = 0; z < 16; ++z) { float d = hv[z] - mean; var += d * d; }
  var *= (1.0f / 16.0f);
  float istd = 1.0f / sqrtf(var + 1e-5f);
  float g = bn_g[f], bb = bn_b[f], ow = out_w[f];
  float contrib[16];
  #pragma unroll
  for (int z = 0; z < 16; ++z)
    contrib[z] = softplus_f((hv[z] - mean) * istd * g + bb) * ow;

  const int lane = tid & 63, wv = tid >> 6;
  #pragma unroll
  for (int m = 32; m > 0; m >>= 1) {
    #pragma unroll
    for (int z = 0; z < 16; ++z) contrib[z] += __shfl_xor(contrib[z], m, 64);
  }
  if (lane == 0) {
    #pragma unroll
    for (int z = 0; z < 16; ++z) part[wv][z] = contrib[z];
  }
  __syncthreads();
  if (tid < 16) {
    float s = out_b[0];
    #pragma unroll
    for (int w8 = 0; w8 < 8; ++w8) s += part[w8][tid];
    out[tid] = 1.0f / (1.0f + expf(-s));
  }
}

extern "C" void kernel_launch(void* const* d_in, const int* in_sizes, int n_in,
                              void* d_out, int out_size, void* d_ws, size_t ws_size,
                              hipStream_t stream) {
  const float* xyz = (const float*)d_in[0];
  const int*   Z   = (const int*)d_in[1];
  const float* emb = (const float*)d_in[2];
  const float* c0[8]; const float* c1[8];
  for (int i = 0; i < 8; ++i) {
    c0[i] = (const float*)d_in[3 + i];
    c1[i] = (const float*)d_in[11 + i];
  }
  const float* fc_w  = (const float*)d_in[19];
  const float* fc_b  = (const float*)d_in[20];
  const float* bn_g  = (const float*)d_in[21];
  const float* bn_b  = (const float*)d_in[22];
  const float* out_w = (const float*)d_in[23];
  const float* out_b = (const float*)d_in[24];
  float* out = (float*)d_out;

  float* wsf = (float*)d_ws;
  const size_t TAB_ELEMS = (size_t)NT * 16;
  float* t0 = wsf;
  float* t1 = t0 + TAB_ELEMS;
  float* f1 = t1 + TAB_ELEMS;
  float* f2 = f1 + (size_t)B_SZ * N_ATOM * 4;

  table_kernel<<<2 * (NT / 64), 256, 0, stream>>>(
      c0[0], c0[1], c0[2], c0[3], c0[4], c0[5], c0[6], c0[7],
      c1[0], c1[1], c1[2], c1[3], c1[4], c1[5], c1[6], c1[7], t0, t1);

  const int conv_blocks = (B_SZ * N_ATOM) / ROWS_BLK;   // 286, exact
  conv_kernel<<<conv_blocks, 256, 0, stream>>>(xyz, Z, emb, (const float*)nullptr,
                                               t0, f1, 1);
  conv_kernel<<<conv_blocks, 256, 0, stream>>>(xyz, Z, emb, f1,
                                               t1, f2, 0);

  tail_kernel<<<1, 512, 0, stream>>>(f1, f2, fc_w, fc_b, bn_g, bn_b,
                                     out_w, out_b, out);
}

// Round 6
// 203.830 us; speedup vs baseline: 1.3703x; 1.3703x over previous
//
#include <hip/hip_runtime.h>
#include <hip/hip_bf16.h>
#include <math.h>

#define B_SZ   16
#define N_ATOM 286
#define NT     1024            // table entries, r_e = 3*e/(NT-1)
#define HIDW   150
#define FF_DIM 512
#define EPB    8               // table entries per block (2 per wave)

__device__ __forceinline__ float softplus_f(float x) {
  return fmaxf(x, 0.0f) + log1pf(expf(-fabsf(x)));
}
// torch Softplus(beta=5): softplus(5x)/5
__device__ __forceinline__ float sp5_f(float x) {
  float t = 5.0f * x;
  return (fmaxf(t, 0.0f) + log1pf(expf(-fabsf(t)))) * 0.2f;
}

// One hidden layer 150->150 for this wave's 2 entries (e0, e0+1).
// lane = output neuron (3 chunks of 64); W streamed from global (coalesced,
// L1-shared across waves); activations via uniform ds_read_b64 broadcast.
// Act columns are wave-private -> no barriers anywhere.
__device__ __forceinline__ void hidden_layer(
    const float* __restrict__ W, const float* __restrict__ bias,
    const float* __restrict__ src, float* __restrict__ dst,
    int lane, int e0) {
  const int o2 = 128 + lane;
  const int o2c = (o2 < HIDW) ? o2 : (HIDW - 1);
  float acc00 = bias[lane],     acc01 = acc00;
  float acc10 = bias[64 + lane], acc11 = acc10;
  float acc20 = bias[o2c],      acc21 = acc20;
  #pragma unroll 5
  for (int i = 0; i < HIDW; ++i) {
    const float2 hv = *(const float2*)(src + i * EPB + e0);  // uniform 8B broadcast
    const float* __restrict__ Wr = W + i * HIDW;
    float wv0 = Wr[lane];
    float wv1 = Wr[64 + lane];
    int idx2 = i * HIDW + o2;                 // clamp last-row overrun (pad lanes)
    idx2 = (idx2 <= HIDW * HIDW - 1) ? idx2 : (HIDW * HIDW - 1);
    float wv2 = W[idx2];
    acc00 = __builtin_fmaf(hv.x, wv0, acc00); acc01 = __builtin_fmaf(hv.y, wv0, acc01);
    acc10 = __builtin_fmaf(hv.x, wv1, acc10); acc11 = __builtin_fmaf(hv.y, wv1, acc11);
    acc20 = __builtin_fmaf(hv.x, wv2, acc20); acc21 = __builtin_fmaf(hv.y, wv2, acc21);
  }
  *(float2*)(dst + lane * EPB + e0)        = make_float2(sp5_f(acc00), sp5_f(acc01));
  *(float2*)(dst + (64 + lane) * EPB + e0) = make_float2(sp5_f(acc10), sp5_f(acc11));
  if (o2 < HIDW)
    *(float2*)(dst + o2 * EPB + e0)        = make_float2(sp5_f(acc20), sp5_f(acc21));
}

// Tabulate radial MLP R(r) at NT points, both clouds in one launch.
// Grid = 2 * NT/EPB = 256 blocks (one per CU). Block = 256 thr = 4 waves,
// each wave owns 2 entries. Zero __syncthreads (act columns wave-private).
__global__ __launch_bounds__(256) void table_kernel(
    const float* __restrict__ a_w0, const float* __restrict__ a_b0,
    const float* __restrict__ a_w1, const float* __restrict__ a_b1,
    const float* __restrict__ a_w2, const float* __restrict__ a_b2,
    const float* __restrict__ a_w3, const float* __restrict__ a_b3,
    const float* __restrict__ c_w0, const float* __restrict__ c_b0,
    const float* __restrict__ c_w1, const float* __restrict__ c_b1,
    const float* __restrict__ c_w2, const float* __restrict__ c_b2,
    const float* __restrict__ c_w3, const float* __restrict__ c_b3,
    float* __restrict__ tab0, float* __restrict__ tab1) {
  __shared__ float actA[HIDW * EPB];   // 4.8 KB
  __shared__ float actB[HIDW * EPB];

  const int nblk = NT / EPB;                       // 128
  const int cloud = (blockIdx.x >= nblk) ? 1 : 0;
  const int blk   = blockIdx.x - cloud * nblk;
  const float* w0 = cloud ? c_w0 : a_w0;  const float* b0 = cloud ? c_b0 : a_b0;
  const float* w1 = cloud ? c_w1 : a_w1;  const float* b1 = cloud ? c_b1 : a_b1;
  const float* w2 = cloud ? c_w2 : a_w2;  const float* b2 = cloud ? c_b2 : a_b2;
  const float* w3 = cloud ? c_w3 : a_w3;  const float* b3 = cloud ? c_b3 : a_b3;
  float* table = cloud ? tab1 : tab0;

  const int tid  = threadIdx.x;
  const int lane = tid & 63;
  const int wave = __builtin_amdgcn_readfirstlane(tid >> 6);
  const int e0   = wave * 2;
  const int gbase = blk * EPB;

  // cosine basis for the wave's two entries
  float x0[3], x1[3];
  #pragma unroll
  for (int k = 0; k < 3; ++k) {
    float r0 = 3.0f * (float)(gbase + e0)     / (float)(NT - 1);
    float r1 = 3.0f * (float)(gbase + e0 + 1) / (float)(NT - 1);
    float d0 = (r0 - 1.5f * (float)k) * (1.0f / 1.5f);
    float d1 = (r1 - 1.5f * (float)k) * (1.0f / 1.5f);
    float c0 = cosf(1.57079632679489662f * d0);
    float c1 = cosf(1.57079632679489662f * d1);
    x0[k] = (fabsf(d0) < 1.0f) ? c0 * c0 : 0.0f;
    x1[k] = (fabsf(d1) < 1.0f) ? c1 * c1 : 0.0f;
  }

  // ---- layer 0: 3 -> 150 ----
  #pragma unroll
  for (int c = 0; c < 3; ++c) {
    int o = lane + 64 * c;
    int oc = (o < HIDW) ? o : (HIDW - 1);
    float w00 = w0[oc], w01 = w0[HIDW + oc], w02 = w0[2 * HIDW + oc], bb = b0[oc];
    float h0 = sp5_f(bb + x0[0] * w00 + x0[1] * w01 + x0[2] * w02);
    float h1 = sp5_f(bb + x1[0] * w00 + x1[1] * w01 + x1[2] * w02);
    if (o < HIDW) *(float2*)(actA + o * EPB + e0) = make_float2(h0, h1);
  }

  // ---- layers 1,2 ----
  hidden_layer(w1, b1, actA, actB, lane, e0);
  hidden_layer(w2, b2, actB, actA, lane, e0);

  // ---- layer 3: 150 -> 16. lanes = 16 outputs x 4 i-groups ----
  {
    const int o  = lane & 15;
    const int ig = lane >> 4;
    float a0 = 0.f, a1 = 0.f;
    for (int i = ig; i < HIDW; i += 4) {
      float wv = w3[i * 16 + o];
      float h0 = actA[i * EPB + e0];
      float h1 = actA[i * EPB + e0 + 1];
      a0 = __builtin_fmaf(h0, wv, a0);
      a1 = __builtin_fmaf(h1, wv, a1);
    }
    a0 += __shfl_xor(a0, 16, 64); a0 += __shfl_xor(a0, 32, 64);
    a1 += __shfl_xor(a1, 16, 64); a1 += __shfl_xor(a1, 32, 64);
    if (lane < 16) {
      float bb = b3[o];
      table[(size_t)(gbase + e0)     * 16 + o] = a0 + bb;
      table[(size_t)(gbase + e0 + 1) * 16 + o] = a1 + bb;
    }
  }
}

// Conv: one wave per output row (z,a). Table lerp rows (128 B contiguous per
// pair) gathered directly from L2 (table is 64 KB, L2-resident). No LDS.
// conv1 fuses the emb[Z] gather (gather=1); conv2 reads feats_in (gather=0).
__global__ __launch_bounds__(256) void conv_kernel(
    const float* __restrict__ xyz, const int* __restrict__ Z,
    const float* __restrict__ emb, const float* __restrict__ feats_in,
    const float* __restrict__ table, float* __restrict__ f_out, int gather) {
  const int wave = threadIdx.x >> 6;
  const int lane = threadIdx.x & 63;
  const int row = blockIdx.x * 4 + wave;
  if (row >= B_SZ * N_ATOM) return;
  const int z = row / N_ATOM, a = row % N_ATOM;
  const float* xz = xyz + (size_t)z * N_ATOM * 3;
  const float ax = xz[a * 3 + 0], ay = xz[a * 3 + 1], az = xz[a * 3 + 2];

  float acc[4] = {0.f, 0.f, 0.f, 0.f};
  float cnt = 0.f;
  for (int b = lane; b < N_ATOM; b += 64) {
    float bx = xz[b * 3 + 0], by = xz[b * 3 + 1], bz = xz[b * 3 + 2];
    float dx = ax - bx, dy = ay - by, dz = az - bz;
    float r = sqrtf(dx * dx + dy * dy + dz * dz + 1e-12f);
    if (r < 3.0f) {
      cnt += 1.0f;
      float t = r * ((float)(NT - 1) / 3.0f);
      int idx = (int)t;
      if (idx > NT - 2) idx = NT - 2;
      float fr = t - (float)idx;
      const float4* T = (const float4*)(table + (size_t)idx * 16);
      float4 fb;
      if (gather) {
        int zi = Z[z * N_ATOM + b];
        fb = *(const float4*)(emb + (size_t)zi * 4);
      } else {
        fb = *(const float4*)(feats_in + ((size_t)z * N_ATOM + b) * 4);
      }
      #pragma unroll
      for (int i = 0; i < 4; ++i) {
        float4 r0 = T[i], r1 = T[i + 4];
        float v0 = r0.x + fr * (r1.x - r0.x);
        float v1 = r0.y + fr * (r1.y - r0.y);
        float v2 = r0.z + fr * (r1.z - r0.z);
        float v3 = r0.w + fr * (r1.w - r0.w);
        acc[i] += v0 * fb.x + v1 * fb.y + v2 * fb.z + v3 * fb.w;
      }
    }
  }
  #pragma unroll
  for (int m = 32; m > 0; m >>= 1) {
    #pragma unroll
    for (int i = 0; i < 4; ++i) acc[i] += __shfl_xor(acc[i], m, 64);
    cnt += __shfl_xor(cnt, m, 64);
  }
  if (lane == 0) {
    float nb = cnt < 1.0f ? 1.0f : cnt;
    float sc = 1.0f / sqrtf(nb);
    float4 o;
    o.x = acc[0] * sc; o.y = acc[1] * sc; o.z = acc[2] * sc; o.w = acc[3] * sc;
    *(float4*)(f_out + (size_t)row * 4) = o;
  }
}

// L2 pool over atoms -> FC(8->512)+softplus -> batchnorm over B -> softplus
// -> FC(512->1) -> sigmoid.   Single block of 512 threads.
__global__ __launch_bounds__(512) void tail_kernel(
    const float* __restrict__ f1, const float* __restrict__ f2,
    const float* __restrict__ fc_w, const float* __restrict__ fc_b,
    const float* __restrict__ bn_g, const float* __restrict__ bn_b,
    const float* __restrict__ out_w, const float* __restrict__ out_b,
    float* __restrict__ out) {
  __shared__ float pooled[16][8];
  __shared__ float part[8][16];
  const int tid = threadIdx.x;

  // pooling: 4 threads per (z,c) column, 4-lane shuffle reduce
  {
    int pair = tid >> 2;            // 0..127
    int sub  = tid & 3;
    int z = pair >> 3, c = pair & 7;
    const float* src = (c < 4) ? f1 : f2;
    int cc = c & 3;
    float s = 0.f;
    for (int a = sub; a < N_ATOM; a += 4) {
      float v = src[((size_t)z * N_ATOM + a) * 4 + cc];
      s += v * v;
    }
    s += __shfl_xor(s, 1, 64);
    s += __shfl_xor(s, 2, 64);
    if (sub == 0) pooled[z][c] = sqrtf(s);
  }
  __syncthreads();

  const int f = tid;
  float hv[16];
  float mean = 0.f;
  #pragma unroll
  for (int z = 0; z < 16; ++z) {
    float a = fc_b[f];
    #pragma unroll
    for (int c = 0; c < 8; ++c) a += pooled[z][c] * fc_w[c * FF_DIM + f];
    hv[z] = softplus_f(a);
    mean += hv[z];
  }
  mean *= (1.0f / 16.0f);
  float var = 0.f;
  #pragma unroll
  for (int z = 0; z < 16; ++z) { float d = hv[z] - mean; var += d * d; }
  var *= (1.0f / 16.0f);
  float istd = 1.0f / sqrtf(var + 1e-5f);
  float g = bn_g[f], bb = bn_b[f], ow = out_w[f];
  float contrib[16];
  #pragma unroll
  for (int z = 0; z < 16; ++z)
    contrib[z] = softplus_f((hv[z] - mean) * istd * g + bb) * ow;

  const int lane = tid & 63, wv = tid >> 6;
  #pragma unroll
  for (int m = 32; m > 0; m >>= 1) {
    #pragma unroll
    for (int z = 0; z < 16; ++z) contrib[z] += __shfl_xor(contrib[z], m, 64);
  }
  if (lane == 0) {
    #pragma unroll
    for (int z = 0; z < 16; ++z) part[wv][z] = contrib[z];
  }
  __syncthreads();
  if (tid < 16) {
    float s = out_b[0];
    #pragma unroll
    for (int w8 = 0; w8 < 8; ++w8) s += part[w8][tid];
    out[tid] = 1.0f / (1.0f + expf(-s));
  }
}

extern "C" void kernel_launch(void* const* d_in, const int* in_sizes, int n_in,
                              void* d_out, int out_size, void* d_ws, size_t ws_size,
                              hipStream_t stream) {
  const float* xyz = (const float*)d_in[0];
  const int*   Z   = (const int*)d_in[1];
  const float* emb = (const float*)d_in[2];
  const float* c0[8]; const float* c1[8];
  for (int i = 0; i < 8; ++i) {
    c0[i] = (const float*)d_in[3 + i];
    c1[i] = (const float*)d_in[11 + i];
  }
  const float* fc_w  = (const float*)d_in[19];
  const float* fc_b  = (const float*)d_in[20];
  const float* bn_g  = (const float*)d_in[21];
  const float* bn_b  = (const float*)d_in[22];
  const float* out_w = (const float*)d_in[23];
  const float* out_b = (const float*)d_in[24];
  float* out = (float*)d_out;

  float* wsf = (float*)d_ws;
  const size_t TAB_ELEMS = (size_t)NT * 16;
  float* t0 = wsf;
  float* t1 = t0 + TAB_ELEMS;
  float* f1 = t1 + TAB_ELEMS;
  float* f2 = f1 + (size_t)B_SZ * N_ATOM * 4;

  table_kernel<<<2 * (NT / EPB), 256, 0, stream>>>(
      c0[0], c0[1], c0[2], c0[3], c0[4], c0[5], c0[6], c0[7],
      c1[0], c1[1], c1[2], c1[3], c1[4], c1[5], c1[6], c1[7], t0, t1);

  const int conv_blocks = (B_SZ * N_ATOM + 3) / 4;   // 1144
  conv_kernel<<<conv_blocks, 256, 0, stream>>>(xyz, Z, emb, (const float*)nullptr,
                                               t0, f1, 1);
  conv_kernel<<<conv_blocks, 256, 0, stream>>>(xyz, Z, emb, f1,
                                               t1, f2, 0);

  tail_kernel<<<1, 512, 0, stream>>>(f1, f2, fc_w, fc_b, bn_g, bn_b,
                                     out_w, out_b, out);
}

// Round 7
// 196.697 us; speedup vs baseline: 1.4200x; 1.0363x over previous
//
#include <hip/hip_runtime.h>
#include <hip/hip_bf16.h>
#include <hip/hip_fp16.h>
#include <math.h>

#define B_SZ   16
#define N_ATOM 286
#define NT     1024            // table entries, r_e = 3*e/(NT-1)
#define HIDW   150
#define FF_DIM 512
#define WPAD   152             // padded row length (38 float4)
#define WROWS  151             // 150 weight rows + 1 bias row

__device__ __forceinline__ float softplus_f(float x) {
  return fmaxf(x, 0.0f) + log1pf(expf(-fabsf(x)));
}
// torch Softplus(beta=5): softplus(5x)/5
__device__ __forceinline__ float sp5_f(float x) {
  float t = 5.0f * x;
  return (fmaxf(t, 0.0f) + log1pf(expf(-fabsf(t)))) * 0.2f;
}

// Pack the four 150x150 hidden matrices (+bias as row 150) into [151][152]
// float4-friendly layout: Wp[m][i][o], m: 0=c0w1 1=c0w2 2=c1w1 3=c1w2.
__global__ __launch_bounds__(256) void prep_kernel(
    const float* __restrict__ w1a, const float* __restrict__ b1a,
    const float* __restrict__ w2a, const float* __restrict__ b2a,
    const float* __restrict__ w1c, const float* __restrict__ b1c,
    const float* __restrict__ w2c, const float* __restrict__ b2c,
    float* __restrict__ Wp) {
  const int m = blockIdx.y;
  const float* W  = (m == 0) ? w1a : (m == 1) ? w2a : (m == 2) ? w1c : w2c;
  const float* Bb = (m == 0) ? b1a : (m == 1) ? b2a : (m == 2) ? b1c : b2c;
  int idx = blockIdx.x * 256 + threadIdx.x;
  if (idx < WROWS * WPAD) {
    int i = idx / WPAD, o = idx % WPAD;
    float v = 0.0f;
    if (o < HIDW) v = (i < HIDW) ? W[i * HIDW + o] : Bb[o];
    Wp[(size_t)m * WROWS * WPAD + idx] = v;
  }
}

// One hidden layer 150->150 for this wave's 2 entries (e0, e0+1).
// lane jj (0..37) owns outputs 4jj..4jj+3; one coalesced float4 weight load
// per reduction step, unroll-8 pipelined. Activations via uniform LDS
// broadcast. Act columns are wave-private -> no barriers.
__device__ __forceinline__ void hidden_layer_v2(
    const float* __restrict__ Wp,    // [151][152], row 150 = bias
    const float* __restrict__ src,   // act LDS, layout [i*8 + e]
    float* __restrict__ dst,
    int jj, int e0) {
  const float4 bb = *(const float4*)(Wp + HIDW * WPAD + 4 * jj);
  float4 a0 = bb, a1 = bb;          // a0: entry e0, a1: entry e0+1
  #pragma unroll 8
  for (int i = 0; i < HIDW; ++i) {
    float4 wv = *(const float4*)(Wp + i * WPAD + 4 * jj);
    float2 h  = *(const float2*)(src + i * 8 + e0);   // uniform broadcast
    a0.x = __builtin_fmaf(h.x, wv.x, a0.x); a1.x = __builtin_fmaf(h.y, wv.x, a1.x);
    a0.y = __builtin_fmaf(h.x, wv.y, a0.y); a1.y = __builtin_fmaf(h.y, wv.y, a1.y);
    a0.z = __builtin_fmaf(h.x, wv.z, a0.z); a1.z = __builtin_fmaf(h.y, wv.z, a1.z);
    a0.w = __builtin_fmaf(h.x, wv.w, a0.w); a1.w = __builtin_fmaf(h.y, wv.w, a1.w);
  }
  *(float2*)(dst + (4 * jj + 0) * 8 + e0) = make_float2(sp5_f(a0.x), sp5_f(a1.x));
  *(float2*)(dst + (4 * jj + 1) * 8 + e0) = make_float2(sp5_f(a0.y), sp5_f(a1.y));
  *(float2*)(dst + (4 * jj + 2) * 8 + e0) = make_float2(sp5_f(a0.z), sp5_f(a1.z));
  *(float2*)(dst + (4 * jj + 3) * 8 + e0) = make_float2(sp5_f(a0.w), sp5_f(a1.w));
}

// Tabulate radial MLP R(r) at NT points, both clouds in one launch.
// Grid = 2*NT/8 = 256 blocks. Block = 4 waves, 2 entries per wave.
// Output table in fp16 (32 B per entry row of 16 values).
__global__ __launch_bounds__(256) void table_kernel(
    const float* __restrict__ a_w0, const float* __restrict__ a_b0,
    const float* __restrict__ a_w3, const float* __restrict__ a_b3,
    const float* __restrict__ c_w0, const float* __restrict__ c_b0,
    const float* __restrict__ c_w3, const float* __restrict__ c_b3,
    const float* __restrict__ Wp,
    __half* __restrict__ tabh0, __half* __restrict__ tabh1) {
  __shared__ float actA[WPAD * 8];   // 4.9 KB, [o*8 + e], e = wave*2 + {0,1}
  __shared__ float actB[WPAD * 8];

  const int nblk = NT / 8;                         // 128
  const int cloud = (blockIdx.x >= nblk) ? 1 : 0;
  const int blk   = blockIdx.x - cloud * nblk;
  const float* w0 = cloud ? c_w0 : a_w0;  const float* b0 = cloud ? c_b0 : a_b0;
  const float* w3 = cloud ? c_w3 : a_w3;  const float* b3 = cloud ? c_b3 : a_b3;
  const float* Wp1 = Wp + (size_t)(cloud * 2)     * WROWS * WPAD;
  const float* Wp2 = Wp + (size_t)(cloud * 2 + 1) * WROWS * WPAD;
  __half* table = cloud ? tabh1 : tabh0;

  const int tid  = threadIdx.x;
  const int lane = tid & 63;
  const int wave = __builtin_amdgcn_readfirstlane(tid >> 6);
  const int e0   = wave * 2;
  const int gbase = blk * 8;
  const int jj = (lane < 38) ? lane : 37;          // weight-column group

  // cosine basis for the wave's two entries
  float x0[3], x1[3];
  #pragma unroll
  for (int k = 0; k < 3; ++k) {
    float r0 = 3.0f * (float)(gbase + e0)     / (float)(NT - 1);
    float r1 = 3.0f * (float)(gbase + e0 + 1) / (float)(NT - 1);
    float d0 = (r0 - 1.5f * (float)k) * (1.0f / 1.5f);
    float d1 = (r1 - 1.5f * (float)k) * (1.0f / 1.5f);
    float c0 = cosf(1.57079632679489662f * d0);
    float c1 = cosf(1.57079632679489662f * d1);
    x0[k] = (fabsf(d0) < 1.0f) ? c0 * c0 : 0.0f;
    x1[k] = (fabsf(d1) < 1.0f) ? c1 * c1 : 0.0f;
  }

  // ---- layer 0: 3 -> 150 ----
  #pragma unroll
  for (int c = 0; c < 3; ++c) {
    int o = lane + 64 * c;
    int oc = (o < HIDW) ? o : (HIDW - 1);
    float w00 = w0[oc], w01 = w0[HIDW + oc], w02 = w0[2 * HIDW + oc], bb = b0[oc];
    float h0 = sp5_f(bb + x0[0] * w00 + x0[1] * w01 + x0[2] * w02);
    float h1 = sp5_f(bb + x1[0] * w00 + x1[1] * w01 + x1[2] * w02);
    if (o < HIDW) *(float2*)(actA + o * 8 + e0) = make_float2(h0, h1);
  }
  // wave-private columns: no barrier needed

  // ---- layers 1,2 ----
  hidden_layer_v2(Wp1, actA, actB, jj, e0);
  hidden_layer_v2(Wp2, actB, actA, jj, e0);

  // ---- layer 3: 150 -> 16. lanes = 16 outputs x 4 i-groups ----
  {
    const int o  = lane & 15;
    const int ig = lane >> 4;
    float a0 = 0.f, a1 = 0.f;
    for (int i = ig; i < HIDW; i += 4) {
      float wv = w3[i * 16 + o];
      float h0 = actA[i * 8 + e0];
      float h1 = actA[i * 8 + e0 + 1];
      a0 = __builtin_fmaf(h0, wv, a0);
      a1 = __builtin_fmaf(h1, wv, a1);
    }
    a0 += __shfl_xor(a0, 16, 64); a0 += __shfl_xor(a0, 32, 64);
    a1 += __shfl_xor(a1, 16, 64); a1 += __shfl_xor(a1, 32, 64);
    if (lane < 16) {
      float bb = b3[o];
      table[(size_t)(gbase + e0)     * 16 + o] = __float2half(a0 + bb);
      table[(size_t)(gbase + e0 + 1) * 16 + o] = __float2half(a1 + bb);
    }
  }
}

__device__ __forceinline__ void cvt8(uint4 q, float* out) {
  const __half2* h = (const __half2*)&q;
  #pragma unroll
  for (int k = 0; k < 4; ++k) {
    float2 f = __half22float2(h[k]);
    out[2 * k] = f.x; out[2 * k + 1] = f.y;
  }
}

// Conv: one wave per output row (z,a). fp16 table: lerp pair = 64 contiguous
// bytes (rows idx, idx+1) = 4 uint4 gathers from L2. No LDS.
// conv1 fuses the emb[Z] gather (gather=1); conv2 reads feats_in (gather=0).
__global__ __launch_bounds__(256) void conv_kernel(
    const float* __restrict__ xyz, const int* __restrict__ Z,
    const float* __restrict__ emb, const float* __restrict__ feats_in,
    const __half* __restrict__ tabh, float* __restrict__ f_out, int gather) {
  const int wave = threadIdx.x >> 6;
  const int lane = threadIdx.x & 63;
  const int row = blockIdx.x * 4 + wave;
  if (row >= B_SZ * N_ATOM) return;
  const int z = row / N_ATOM, a = row % N_ATOM;
  const float* xz = xyz + (size_t)z * N_ATOM * 3;
  const float ax = xz[a * 3 + 0], ay = xz[a * 3 + 1], az = xz[a * 3 + 2];

  float acc[4] = {0.f, 0.f, 0.f, 0.f};
  float cnt = 0.f;
  for (int b = lane; b < N_ATOM; b += 64) {
    float bx = xz[b * 3 + 0], by = xz[b * 3 + 1], bz = xz[b * 3 + 2];
    float dx = ax - bx, dy = ay - by, dz = az - bz;
    float r = sqrtf(dx * dx + dy * dy + dz * dz + 1e-12f);
    if (r < 3.0f) {
      cnt += 1.0f;
      float t = r * ((float)(NT - 1) / 3.0f);
      int idx = (int)t;
      if (idx > NT - 2) idx = NT - 2;
      float fr = t - (float)idx;
      const uint4* Tp = (const uint4*)(tabh + (size_t)idx * 16);  // 32B-aligned
      uint4 q0 = Tp[0], q1 = Tp[1], q2 = Tp[2], q3 = Tp[3];
      float4 fb;
      if (gather) {
        int zi = Z[z * N_ATOM + b];
        fb = *(const float4*)(emb + (size_t)zi * 4);
      } else {
        fb = *(const float4*)(feats_in + ((size_t)z * N_ATOM + b) * 4);
      }
      float r0[16], r1[16];
      cvt8(q0, r0); cvt8(q1, r0 + 8);
      cvt8(q2, r1); cvt8(q3, r1 + 8);
      #pragma unroll
      for (int i = 0; i < 4; ++i) {
        float v0 = r0[4 * i + 0] + fr * (r1[4 * i + 0] - r0[4 * i + 0]);
        float v1 = r0[4 * i + 1] + fr * (r1[4 * i + 1] - r0[4 * i + 1]);
        float v2 = r0[4 * i + 2] + fr * (r1[4 * i + 2] - r0[4 * i + 2]);
        float v3 = r0[4 * i + 3] + fr * (r1[4 * i + 3] - r0[4 * i + 3]);
        acc[i] += v0 * fb.x + v1 * fb.y + v2 * fb.z + v3 * fb.w;
      }
    }
  }
  #pragma unroll
  for (int m = 32; m > 0; m >>= 1) {
    #pragma unroll
    for (int i = 0; i < 4; ++i) acc[i] += __shfl_xor(acc[i], m, 64);
    cnt += __shfl_xor(cnt, m, 64);
  }
  if (lane == 0) {
    float nb = cnt < 1.0f ? 1.0f : cnt;
    float sc = 1.0f / sqrtf(nb);
    float4 o;
    o.x = acc[0] * sc; o.y = acc[1] * sc; o.z = acc[2] * sc; o.w = acc[3] * sc;
    *(float4*)(f_out + (size_t)row * 4) = o;
  }
}

// L2 pool over atoms -> FC(8->512)+softplus -> batchnorm over B -> softplus
// -> FC(512->1) -> sigmoid.   Single block of 512 threads.
__global__ __launch_bounds__(512) void tail_kernel(
    const float* __restrict__ f1, const float* __restrict__ f2,
    const float* __restrict__ fc_w, const float* __restrict__ fc_b,
    const float* __restrict__ bn_g, const float* __restrict__ bn_b,
    const float* __restrict__ out_w, const float* __restrict__ out_b,
    float* __restrict__ out) {
  __shared__ float pooled[16][8];
  __shared__ float part[8][16];
  const int tid = threadIdx.x;

  // pooling: 4 threads per (z,c) column, 4-lane shuffle reduce
  {
    int pair = tid >> 2;            // 0..127
    int sub  = tid & 3;
    int z = pair >> 3, c = pair & 7;
    const float* src = (c < 4) ? f1 : f2;
    int cc = c & 3;
    float s = 0.f;
    for (int a = sub; a < N_ATOM; a += 4) {
      float v = src[((size_t)z * N_ATOM + a) * 4 + cc];
      s += v * v;
    }
    s += __shfl_xor(s, 1, 64);
    s += __shfl_xor(s, 2, 64);
    if (sub == 0) pooled[z][c] = sqrtf(s);
  }
  __syncthreads();

  const int f = tid;
  float hv[16];
  float mean = 0.f;
  #pragma unroll
  for (int z = 0; z < 16; ++z) {
    float a = fc_b[f];
    #pragma unroll
    for (int c = 0; c < 8; ++c) a += pooled[z][c] * fc_w[c * FF_DIM + f];
    hv[z] = softplus_f(a);
    mean += hv[z];
  }
  mean *= (1.0f / 16.0f);
  float var = 0.f;
  #pragma unroll
  for (int z = 0; z < 16; ++z) { float d = hv[z] - mean; var += d * d; }
  var *= (1.0f / 16.0f);
  float istd = 1.0f / sqrtf(var + 1e-5f);
  float g = bn_g[f], bb = bn_b[f], ow = out_w[f];
  float contrib[16];
  #pragma unroll
  for (int z = 0; z < 16; ++z)
    contrib[z] = softplus_f((hv[z] - mean) * istd * g + bb) * ow;

  const int lane = tid & 63, wv = tid >> 6;
  #pragma unroll
  for (int m = 32; m > 0; m >>= 1) {
    #pragma unroll
    for (int z = 0; z < 16; ++z) contrib[z] += __shfl_xor(contrib[z], m, 64);
  }
  if (lane == 0) {
    #pragma unroll
    for (int z = 0; z < 16; ++z) part[wv][z] = contrib[z];
  }
  __syncthreads();
  if (tid < 16) {
    float s = out_b[0];
    #pragma unroll
    for (int w8 = 0; w8 < 8; ++w8) s += part[w8][tid];
    out[tid] = 1.0f / (1.0f + expf(-s));
  }
}

extern "C" void kernel_launch(void* const* d_in, const int* in_sizes, int n_in,
                              void* d_out, int out_size, void* d_ws, size_t ws_size,
                              hipStream_t stream) {
  const float* xyz = (const float*)d_in[0];
  const int*   Z   = (const int*)d_in[1];
  const float* emb = (const float*)d_in[2];
  const float* c0[8]; const float* c1[8];
  for (int i = 0; i < 8; ++i) {
    c0[i] = (const float*)d_in[3 + i];
    c1[i] = (const float*)d_in[11 + i];
  }
  const float* fc_w  = (const float*)d_in[19];
  const float* fc_b  = (const float*)d_in[20];
  const float* bn_g  = (const float*)d_in[21];
  const float* bn_b  = (const float*)d_in[22];
  const float* out_w = (const float*)d_in[23];
  const float* out_b = (const float*)d_in[24];
  float* out = (float*)d_out;

  // ws layout (fp32 region first, then fp16 tables)
  float* wsf = (float*)d_ws;
  float* Wp = wsf;                                             // 4*151*152 f32
  float* f1 = Wp + (size_t)4 * WROWS * WPAD;                   // 16*286*4 f32
  float* f2 = f1 + (size_t)B_SZ * N_ATOM * 4;
  __half* tabh0 = (__half*)(f2 + (size_t)B_SZ * N_ATOM * 4);   // NT*16 f16
  __half* tabh1 = tabh0 + (size_t)NT * 16;

  {
    dim3 g((WROWS * WPAD + 255) / 256, 4);
    prep_kernel<<<g, 256, 0, stream>>>(c0[2], c0[3], c0[4], c0[5],
                                       c1[2], c1[3], c1[4], c1[5], Wp);
  }

  table_kernel<<<2 * (NT / 8), 256, 0, stream>>>(
      c0[0], c0[1], c0[6], c0[7],
      c1[0], c1[1], c1[6], c1[7],
      Wp, tabh0, tabh1);

  const int conv_blocks = (B_SZ * N_ATOM + 3) / 4;   // 1144
  conv_kernel<<<conv_blocks, 256, 0, stream>>>(xyz, Z, emb, (const float*)nullptr,
                                               tabh0, f1, 1);
  conv_kernel<<<conv_blocks, 256, 0, stream>>>(xyz, Z, emb, f1,
                                               tabh1, f2, 0);

  tail_kernel<<<1, 512, 0, stream>>>(f1, f2, fc_w, fc_b, bn_g, bn_b,
                                     out_w, out_b, out);
}